// Round 9
// baseline (283.297 us; speedup 1.0000x reference)
//
#include <hip/hip_runtime.h>
#include <hip/hip_bf16.h>

// Problem constants
#define BB   128
#define SS   168
#define DM   128
#define LL   2
#define II   256
#define NN   16
#define RR   8
#define KK   4
#define PP   24
#define MROWS (BB*SS)   // 21504
#define NCH  12         // scan chunks (R9: 8->12, serial path x0.67)
#define TCH  14         // SS / NCH

typedef __attribute__((ext_vector_type(8))) short bf16x8;
typedef __attribute__((ext_vector_type(4))) short bf16x4;
typedef __attribute__((ext_vector_type(4))) float f32x4;

__device__ __forceinline__ float wave_sum(float x) {
#pragma unroll
    for (int off = 32; off > 0; off >>= 1) x += __shfl_xor(x, off);
    return x;
}
__device__ __forceinline__ float siluf(float x) {
    return x / (1.f + __expf(-x));
}
__device__ __forceinline__ float softplusf(float x) {
    return (x > 20.f) ? x : __logf(1.f + __expf(x));
}
__device__ __forceinline__ short f2bf(float x) {   // RNE f32 -> bf16
    unsigned u = __builtin_bit_cast(unsigned, x);
    u = (u + 0x7FFFu + ((u >> 16) & 1u)) >> 16;
    return (short)u;
}
__device__ __forceinline__ bf16x4 pack4(const float* f) {
    bf16x4 r;
#pragma unroll
    for (int j = 0; j < 4; ++j) r[j] = f2bf(f[j]);
    return r;
}
__device__ __forceinline__ bf16x8 pack8(const float* f) {
    bf16x8 r;
#pragma unroll
    for (int j = 0; j < 8; ++j) r[j] = f2bf(f[j]);
    return r;
}

// ---------------------------------------------------------------------------
// Zero-fill (for the atomic rowscale accumulators).
// ---------------------------------------------------------------------------
__global__ __launch_bounds__(256)
void zero_kernel(float* __restrict__ p, int n)
{
    const int i = blockIdx.x * 256 + threadIdx.x;
    if (i < n) p[i] = 0.f;
}

// ---------------------------------------------------------------------------
// bf16-MFMA GEMM (R8-validated): round-0 inner loop, BN=64, BM=32, BK=32,
// LDT=40, 2 barriers/tile, reg-prefetch. rs[m] = row sumsq (rsqrt applied
// here); rso = atomicAdd sumsq accumulator (pre-zeroed). A-side fusions:
// rs*cs (rmsnorm), silu(em) (gate, leading dim lde). Output split at nsplit.
// ---------------------------------------------------------------------------
#define LDT 40
template<bool ACCUM>
__global__ __launch_bounds__(256)
void gemm_mfma(const float* __restrict__ A, const float* __restrict__ W, int K,
               const float* __restrict__ A2, const float* __restrict__ W2, int K2,
               const float* __restrict__ bias,
               const float* __restrict__ r1x, const float* __restrict__ r1w,
               const float* __restrict__ rs, const float* __restrict__ cs,
               const float* __restrict__ em, int lde,
               float* __restrict__ C, float* __restrict__ C2, int nsplit, int ldc,
               float* __restrict__ rso)
{
    __shared__ __align__(16) short Asl[32 * LDT];
    __shared__ __align__(16) short Bsl[64 * LDT];
    __shared__ float red[2][32];
    const int bm = blockIdx.x * 32;
    const int bn = blockIdx.y * 64;
    const int t  = threadIdx.x;
    const int lane = t & 63;
    const int wave = t >> 6;
    const int wr = wave >> 1, wc = wave & 1;
    const int lrow = lane & 15;
    const int lk   = (lane >> 4) * 8;

    f32x4 acc[2];
    acc[0] = (f32x4){0.f, 0.f, 0.f, 0.f};
    acc[1] = (f32x4){0.f, 0.f, 0.f, 0.f};

    const int arow = t >> 3, ak = (t & 7) * 4;    // A: 32 rows x 32 k (4 f/thr)
    const int brow = t >> 2, bk = (t & 3) * 8;    // B: 64 rows x 32 k (8 f/thr)
    const float rsv = rs ? rsqrtf(rs[bm + arow] * (1.f / DM) + 1e-5f) : 1.f;

    float av[4], bv[8], cv[4], ev[4];

#pragma unroll 1
    for (int pass = 0; pass < 2; ++pass) {
        const float* Ap = pass ? A2 : A;
        const float* Wp = pass ? W2 : W;
        const int    Kp = pass ? K2 : K;
        if (!Ap) continue;
        const float* aptr = Ap + (size_t)(bm + arow) * Kp + ak;
        const float* bptr = Wp + (size_t)(bn + brow) * Kp + bk;
        const float* eptr = em ? em + (size_t)(bm + arow) * lde + ak : nullptr;

        // prologue load (k0 = 0)
        *(float4*)&av[0] = *(const float4*)(aptr);
        if (cs) *(float4*)&cv[0] = *(const float4*)&cs[ak];
        if (em) *(float4*)&ev[0] = *(const float4*)(eptr);
        *(float4*)&bv[0] = *(const float4*)(bptr);
        *(float4*)&bv[4] = *(const float4*)(bptr + 4);

#pragma unroll 1
        for (int k0 = 0; k0 < Kp; k0 += 32) {
            __syncthreads();   // previous iteration's LDS reads done
            float as[4];
#pragma unroll
            for (int j = 0; j < 4; ++j) {
                float v = av[j];
                if (cs) v *= rsv * cv[j];
                if (em) v *= siluf(ev[j]);
                as[j] = v;
            }
            *(bf16x4*)&Asl[arow * LDT + ak] = pack4(as);
            *(bf16x8*)&Bsl[brow * LDT + bk] = pack8(bv);
            __syncthreads();
            const int kn = k0 + 32;
            if (kn < Kp) {   // prefetch next tile while MFMA runs
                *(float4*)&av[0] = *(const float4*)(aptr + kn);
                if (cs) *(float4*)&cv[0] = *(const float4*)&cs[kn + ak];
                if (em) *(float4*)&ev[0] = *(const float4*)(eptr + kn);
                *(float4*)&bv[0] = *(const float4*)(bptr + kn);
                *(float4*)&bv[4] = *(const float4*)(bptr + kn + 4);
            }
            const bf16x8 af = *(const bf16x8*)&Asl[(wr * 16 + lrow) * LDT + lk];
            bf16x8 bfr[2];
#pragma unroll
            for (int ni = 0; ni < 2; ++ni)
                bfr[ni] = *(const bf16x8*)&Bsl[(wc * 32 + ni * 16 + lrow) * LDT + lk];
#pragma unroll
            for (int ni = 0; ni < 2; ++ni)
                acc[ni] = __builtin_amdgcn_mfma_f32_16x16x32_bf16(af, bfr[ni], acc[ni], 0, 0, 0);
        }
    }

    // epilogue (split + optional atomic rowscale sumsq)
    const bool hi = (bn >= nsplit);
    float* __restrict__ Cp = hi ? C2 : C;
    const int cb = bn - (hi ? nsplit : 0);
    float p[4] = {0.f, 0.f, 0.f, 0.f};
#pragma unroll
    for (int r = 0; r < 4; ++r) {
        const int row = bm + wr * 16 + (lane >> 4) * 4 + r;
        const float xl = r1x ? r1x[row] : 0.f;
#pragma unroll
        for (int ni = 0; ni < 2; ++ni) {
            const int col = bn + wc * 32 + ni * 16 + lrow;   // logical col
            float v = acc[ni][r];
            if (bias) v += bias[col];
            if (r1x)  v += xl * r1w[col];
            float* cp = &Cp[(size_t)row * ldc + (cb + wc * 32 + ni * 16 + lrow)];
            if (ACCUM) v += *cp;
            *cp = v;
            p[r] += v * v;
        }
    }
    if (rso) {   // partial sumsq (32 cols of this block) -> atomicAdd
#pragma unroll
        for (int m = 1; m < 16; m <<= 1) {
#pragma unroll
            for (int r = 0; r < 4; ++r) p[r] += __shfl_xor(p[r], m);
        }
        if (lrow == 0) {
#pragma unroll
            for (int r = 0; r < 4; ++r)
                red[wc][wr * 16 + (lane >> 4) * 4 + r] = p[r];
        }
        __syncthreads();
        if (t < 32) atomicAdd(&rso[bm + t], red[0][t] + red[1][t]);
    }
}

// ---------------------------------------------------------------------------
// Fused conv + x_proj + scanA per (b, chunk):
//  - causal depthwise conv(K=4)+SiLU -> uts (LDS) + ut (global, for scanB)
//  - x_proj per-thread dots (no cross-lane ops, R7-validated); TCH=14 row
//    mapping: thread i<240 owns n=i/6, rows {sgrp, sgrp+6, sgrp+12 if <14}
//  - scanA: local scan from zero init -> q; P replaced by dtsum[b][ch][i]
//    (P = exp(Ar*dtsum) recomputed in combine — 16.8MB traffic saved)
// ---------------------------------------------------------------------------
__global__ __launch_bounds__(256)
void fusedA_kernel(const float* __restrict__ hs, const float* __restrict__ cw,
                   const float* __restrict__ cb, const float* __restrict__ xw,
                   const float* __restrict__ dtw, const float* __restrict__ dtb,
                   const float* __restrict__ A_log,
                   float* __restrict__ ut, float* __restrict__ sp,
                   float* __restrict__ dtsum_g, float* __restrict__ q)
{
    __shared__ float uts[TCH][II + 4];   // 14 x 260
    __shared__ float lsp[TCH * 40];
    const int b = blockIdx.x;
    const int ch = blockIdx.y;
    const int i = threadIdx.x;
    const int s0 = ch * TCH;

    // ---- conv ----
    {
        const float4 w = *(const float4*)&cw[i * 4];
        const float bi = cb[i];
        const float* hp = hs + (size_t)b * SS * II + i;
        float* up = ut + (size_t)b * SS * II + i;
        float wm3 = (s0 - 3 >= 0) ? hp[(s0 - 3) * II] : 0.f;
        float wm2 = (s0 - 2 >= 0) ? hp[(s0 - 2) * II] : 0.f;
        float wm1 = (s0 - 1 >= 0) ? hp[(s0 - 1) * II] : 0.f;
        for (int s = 0; s < TCH; ++s) {
            const float cur = hp[(s0 + s) * II];
            float a = fmaf(w.x, wm3, fmaf(w.y, wm2, fmaf(w.z, wm1, fmaf(w.w, cur, bi))));
            const float uv = siluf(a);
            up[(s0 + s) * II] = uv;
            uts[s][i] = uv;
            wm3 = wm2; wm2 = wm1; wm1 = cur;
        }
    }
    __syncthreads();

    // ---- x_proj (per-thread dots, no cross-lane ops) ----
    if (i < 240) {
        const int n = i / 6;        // 0..39
        const int sgrp = i % 6;     // rows sgrp, sgrp+6, (+12 if < TCH)
        const float* xwr = xw + (size_t)n * II;
        float acc0 = 0.f, acc1 = 0.f, acc2 = 0.f;
        const int s1 = sgrp + 6, s2 = sgrp + 12;
        const bool has2 = (s2 < TCH);
#pragma unroll 4
        for (int k = 0; k < II; k += 4) {
            const float4 wv = *(const float4*)&xwr[k];
            const float4 u0 = *(const float4*)&uts[sgrp][k];
            acc0 = fmaf(u0.w, wv.w, fmaf(u0.z, wv.z, fmaf(u0.y, wv.y, fmaf(u0.x, wv.x, acc0))));
            const float4 u1 = *(const float4*)&uts[s1][k];
            acc1 = fmaf(u1.w, wv.w, fmaf(u1.z, wv.z, fmaf(u1.y, wv.y, fmaf(u1.x, wv.x, acc1))));
            if (has2) {
                const float4 u2 = *(const float4*)&uts[s2][k];
                acc2 = fmaf(u2.w, wv.w, fmaf(u2.z, wv.z, fmaf(u2.y, wv.y, fmaf(u2.x, wv.x, acc2))));
            }
        }
        lsp[sgrp * 40 + n] = acc0;
        lsp[s1 * 40 + n]   = acc1;
        if (has2) lsp[s2 * 40 + n] = acc2;
    }
    __syncthreads();

    // sp -> global (scanB needs it)
    {
        float* spp = sp + ((size_t)b * SS + s0) * 40;
        for (int idx = i; idx < TCH * 40; idx += 256) spp[idx] = lsp[idx];
    }

    // ---- scanA ----
    float dw[8];
    {
        const float4 w0 = *(const float4*)&dtw[i * 8];
        const float4 w1 = *(const float4*)&dtw[i * 8 + 4];
        dw[0]=w0.x; dw[1]=w0.y; dw[2]=w0.z; dw[3]=w0.w;
        dw[4]=w1.x; dw[5]=w1.y; dw[6]=w1.z; dw[7]=w1.w;
    }
    const float bdt = dtb[i];
    float Ar[NN];
#pragma unroll
    for (int n = 0; n < NN; ++n) Ar[n] = -__expf(A_log[i * NN + n]);

    float st[NN];
#pragma unroll
    for (int n = 0; n < NN; ++n) st[n] = 0.f;
    float dtsum = 0.f;

    for (int s = 0; s < TCH; ++s) {
        const float uv = uts[s][i];
        const float* r = &lsp[s * 40];
        const float p0 = fmaf(r[1], dw[1], r[0] * dw[0]);
        const float p1 = fmaf(r[3], dw[3], r[2] * dw[2]);
        const float p2 = fmaf(r[5], dw[5], r[4] * dw[4]);
        const float p3 = fmaf(r[7], dw[7], r[6] * dw[6]);
        const float dtv = softplusf(bdt + (p0 + p1) + (p2 + p3));
        const float du = dtv * uv;
        dtsum += dtv;
#pragma unroll
        for (int n = 0; n < NN; ++n) {
            const float a = __expf(dtv * Ar[n]);
            st[n] = fmaf(a, st[n], du * r[8 + n]);
        }
    }
    dtsum_g[((size_t)b * NCH + ch) * II + i] = dtsum;
    float* qp = q + (((size_t)b * NCH + ch) * NN) * II + i;
#pragma unroll
    for (int n = 0; n < NN; ++n) qp[n * II] = st[n];
}

// ---------------------------------------------------------------------------
// Combine: q[ch] <- state BEFORE chunk ch. thread = (b, i).
// P recomputed as exp(Ar[n] * dtsum[ch]) (identical formula to R8's fusedA).
// ---------------------------------------------------------------------------
__global__ __launch_bounds__(256)
void combine_kernel(const float* __restrict__ dtsum_g,
                    const float* __restrict__ A_log, float* __restrict__ q)
{
    const int b = blockIdx.x;
    const int i = threadIdx.x;
    float Ar[NN];
#pragma unroll
    for (int n = 0; n < NN; ++n) Ar[n] = -__expf(A_log[i * NN + n]);
    float ds[NCH];
#pragma unroll
    for (int ch = 0; ch < NCH; ++ch)
        ds[ch] = dtsum_g[((size_t)b * NCH + ch) * II + i];
#pragma unroll
    for (int n = 0; n < NN; ++n) {
        float cur = 0.f;
#pragma unroll
        for (int ch = 0; ch < NCH; ++ch) {
            const size_t idx = (((size_t)b * NCH + ch) * NN + n) * II + i;
            const float Pv = __expf(Ar[n] * ds[ch]);
            const float qv = q[idx];
            q[idx] = cur;
            cur = fmaf(Pv, cur, qv);
        }
    }
}

// ---------------------------------------------------------------------------
// Scan pass B: full scan with proper init; y = st·C + ut*Dp  (gate applied
// later inside the out_proj GEMM staging).
// ---------------------------------------------------------------------------
__global__ __launch_bounds__(256)
void scanB_kernel(const float* __restrict__ ut, const float* __restrict__ sp,
                  const float* __restrict__ qinit,
                  const float* __restrict__ dtw, const float* __restrict__ dtb,
                  const float* __restrict__ A_log, const float* __restrict__ Dp,
                  float* __restrict__ y)
{
    __shared__ float lsp[TCH * 40];
    const int b = blockIdx.x;
    const int ch = blockIdx.y;
    const int i = threadIdx.x;
    const int s0 = ch * TCH;
    {
        const float* spp = sp + ((size_t)b * SS + s0) * 40;
        for (int idx = i; idx < TCH * 40; idx += 256) lsp[idx] = spp[idx];
    }
    float dw[8];
    {
        const float4 w0 = *(const float4*)&dtw[i * 8];
        const float4 w1 = *(const float4*)&dtw[i * 8 + 4];
        dw[0]=w0.x; dw[1]=w0.y; dw[2]=w0.z; dw[3]=w0.w;
        dw[4]=w1.x; dw[5]=w1.y; dw[6]=w1.z; dw[7]=w1.w;
    }
    const float bdt = dtb[i];
    const float Dv = Dp[i];
    float Ar[NN];
#pragma unroll
    for (int n = 0; n < NN; ++n) Ar[n] = -__expf(A_log[i * NN + n]);

    float st[NN];
    {
        const float* qp = qinit + (((size_t)b * NCH + ch) * NN) * II + i;
#pragma unroll
        for (int n = 0; n < NN; ++n) st[n] = qp[n * II];
    }

    const float* utp = ut + ((size_t)b * SS + s0) * II + i;
    float* yp = y + ((size_t)b * SS + s0) * II + i;
    __syncthreads();

    float uv = utp[0];
    for (int s = 0; s < TCH; ++s) {
        const int sn = (s + 1 < TCH) ? s + 1 : s;
        const float uv_n = utp[sn * II];
        const float* r = &lsp[s * 40];
        const float p0 = fmaf(r[1], dw[1], r[0] * dw[0]);
        const float p1 = fmaf(r[3], dw[3], r[2] * dw[2]);
        const float p2 = fmaf(r[5], dw[5], r[4] * dw[4]);
        const float p3 = fmaf(r[7], dw[7], r[6] * dw[6]);
        const float dtv = softplusf(bdt + (p0 + p1) + (p2 + p3));
        const float du = dtv * uv;
        float y0 = 0.f, y1 = 0.f, y2 = 0.f, y3 = 0.f;
#pragma unroll
        for (int n = 0; n < NN; n += 4) {
            const float a0 = __expf(dtv * Ar[n + 0]);
            const float a1 = __expf(dtv * Ar[n + 1]);
            const float a2 = __expf(dtv * Ar[n + 2]);
            const float a3 = __expf(dtv * Ar[n + 3]);
            st[n + 0] = fmaf(a0, st[n + 0], du * r[8 + n + 0]);
            st[n + 1] = fmaf(a1, st[n + 1], du * r[8 + n + 1]);
            st[n + 2] = fmaf(a2, st[n + 2], du * r[8 + n + 2]);
            st[n + 3] = fmaf(a3, st[n + 3], du * r[8 + n + 3]);
            y0 = fmaf(st[n + 0], r[24 + n + 0], y0);
            y1 = fmaf(st[n + 1], r[24 + n + 1], y1);
            y2 = fmaf(st[n + 2], r[24 + n + 2], y2);
            y3 = fmaf(st[n + 3], r[24 + n + 3], y3);
        }
        yp[s * II] = (y0 + y1) + (y2 + y3) + uv * Dv;
        uv = uv_n;
    }
}

// ---------------------------------------------------------------------------
// Final head: rmsnorm(h[b,S-1,:]) -> layernorm -> fc -> out[b,p]
// ---------------------------------------------------------------------------
__global__ __launch_bounds__(64)
void final_kernel(const float* __restrict__ h, const float* __restrict__ fnw,
                  const float* __restrict__ lnw, const float* __restrict__ lnb,
                  const float* __restrict__ fcw, const float* __restrict__ fcb,
                  float* __restrict__ out)
{
    __shared__ float last[DM];
    const int b = blockIdx.x;
    const int lane = threadIdx.x;
    const float* hp = &h[((size_t)b * SS + (SS - 1)) * DM];
    const float2 v = *(const float2*)&hp[lane * 2];
    const float ss = wave_sum(v.x * v.x + v.y * v.y);
    const float sc = rsqrtf(ss * (1.f / DM) + 1e-5f);
    const float2 fw = *(const float2*)&fnw[lane * 2];
    const float t0 = v.x * sc * fw.x, t1 = v.y * sc * fw.y;
    const float m = wave_sum(t0 + t1) * (1.f / DM);
    const float d0 = t0 - m, d1 = t1 - m;
    const float var = wave_sum(d0 * d0 + d1 * d1) * (1.f / DM);
    const float iv = rsqrtf(var + 1e-5f);
    const float2 lw = *(const float2*)&lnw[lane * 2];
    const float2 lb = *(const float2*)&lnb[lane * 2];
    last[lane * 2]     = d0 * iv * lw.x + lb.x;
    last[lane * 2 + 1] = d1 * iv * lw.y + lb.y;
    __syncthreads();
    if (lane < PP) {
        float a = fcb[lane];
#pragma unroll 8
        for (int d = 0; d < DM; ++d) a = fmaf(last[d], fcw[lane * DM + d], a);
        out[b * PP + lane] = a;
    }
}

// ---------------------------------------------------------------------------
extern "C" void kernel_launch(void* const* d_in, const int* in_sizes, int n_in,
                              void* d_out, int out_size, void* d_ws, size_t ws_size,
                              hipStream_t stream)
{
    (void)in_sizes; (void)n_in; (void)out_size; (void)ws_size;
    const float* x_load = (const float*)d_in[0];
    const float* x_img  = (const float*)d_in[1];
    const float* x_text = (const float*)d_in[2];
    const float* Wl     = (const float*)d_in[3];
    const float* Wi     = (const float*)d_in[4];
    const float* Wt     = (const float*)d_in[5];
    const float* b_fuse = (const float*)d_in[6];
    const float* mnorm_w= (const float*)d_in[7];
    const float* in_w   = (const float*)d_in[8];
    const float* in_b   = (const float*)d_in[9];
    const float* conv_w = (const float*)d_in[10];
    const float* conv_b = (const float*)d_in[11];
    const float* xp_w   = (const float*)d_in[12];
    const float* dt_w   = (const float*)d_in[13];
    const float* dt_b   = (const float*)d_in[14];
    const float* A_log  = (const float*)d_in[15];
    const float* Dp     = (const float*)d_in[16];
    const float* out_w  = (const float*)d_in[17];
    const float* out_b  = (const float*)d_in[18];
    const float* fnorm_w= (const float*)d_in[19];
    const float* ln_w   = (const float*)d_in[20];
    const float* ln_b   = (const float*)d_in[21];
    const float* fc_w   = (const float*)d_in[22];
    const float* fc_b   = (const float*)d_in[23];

    float* ws  = (float*)d_ws;
    float* h     = ws;                              // [21504][128]
    float* ybuf  = h     + (size_t)MROWS * DM;      // [21504][256] (y; dtsum alias)
    float* hs    = ybuf  + (size_t)MROWS * II;      // [21504][256]
    float* gate  = hs    + (size_t)MROWS * II;      // [21504][256]
    float* ut    = gate  + (size_t)MROWS * II;      // [21504][256]
    float* sp    = ut    + (size_t)MROWS * II;      // [21504][40]
    float* scale0= sp    + (size_t)MROWS * 40;      // [21504] sumsq (fusion)
    float* scale1= scale0 + MROWS;                  // [21504] sumsq (out_proj l0)
    float* q     = scale1 + MROWS;                  // [B][NCH][NN][II] dedicated
    float* dtsum = ybuf;                            // [B][NCH][II] (dead before y)

    const int NSP_NONE = 1 << 30;

    // zero the atomic sumsq accumulators (both) before any GEMM
    zero_kernel<<<(2 * MROWS + 255) / 256, 256, 0, stream>>>(scale0, 2 * MROWS);

    // --- feature fusion (text + img + rank-1 load + bias), sumsq fused ---
    gemm_mfma<false><<<dim3(MROWS / 32, 2), 256, 0, stream>>>(
        x_text, Wt, 768, x_img, Wi, 64, b_fuse, x_load, Wl,
        nullptr, nullptr, nullptr, 0,
        h, nullptr, NSP_NONE, DM, scale0);

    for (int l = 0; l < LL; ++l) {
        const float* sc_in = (l == 0) ? scale0 : scale1;
        // in_proj (rmsnorm fused via rs(sumsq)/cs), hs+gate in ONE dispatch:
        // blocks with logical col < 256 -> hs, >= 256 -> gate.
        gemm_mfma<false><<<dim3(MROWS / 32, 8), 256, 0, stream>>>(
            h, in_w + (size_t)l * 2 * II * DM, DM, nullptr, nullptr, 0,
            in_b + (size_t)l * 2 * II, nullptr, nullptr,
            sc_in, mnorm_w + l * DM, nullptr, 0,
            hs, gate, II, II, nullptr);
        // conv + x_proj + scanA fused
        fusedA_kernel<<<dim3(BB, NCH), 256, 0, stream>>>(
            hs, conv_w + l * II * KK, conv_b + l * II, xp_w + l * 40 * II,
            dt_w + l * II * RR, dt_b + l * II, A_log + l * II * NN,
            ut, sp, dtsum, q);
        combine_kernel<<<BB, 256, 0, stream>>>(dtsum, A_log + l * II * NN, q);
        scanB_kernel<<<dim3(BB, NCH), 256, 0, stream>>>(
            ut, sp, q, dt_w + l * II * RR, dt_b + l * II,
            A_log + l * II * NN, Dp + l * II, ybuf);
        // out_proj with y*silu(gate) fused into A staging; next layer's
        // rmsnorm sumsq accumulated atomically (only needed after l=0).
        gemm_mfma<true><<<dim3(MROWS / 32, 2), 256, 0, stream>>>(
            ybuf, out_w + (size_t)l * DM * II, II, nullptr, nullptr, 0,
            out_b + l * DM, nullptr, nullptr,
            nullptr, nullptr, gate, II,
            h, nullptr, NSP_NONE, DM, (l == 0) ? scale1 : nullptr);
    }

    final_kernel<<<BB, 64, 0, stream>>>(h, fnorm_w, ln_w, ln_b, fc_w, fc_b,
                                        (float*)d_out);
}

// Round 10
// 256.954 us; speedup vs baseline: 1.1025x; 1.1025x over previous
//
#include <hip/hip_runtime.h>
#include <hip/hip_bf16.h>

// Problem constants
#define BB   128
#define SS   168
#define DM   128
#define LL   2
#define II   256
#define NN   16
#define RR   8
#define KK   4
#define PP   24
#define MROWS (BB*SS)   // 21504
#define NCH  12         // scan chunks
#define TCH  14         // SS / NCH (fits one MFMA M=16 tile)

typedef __attribute__((ext_vector_type(8))) short bf16x8;
typedef __attribute__((ext_vector_type(4))) short bf16x4;
typedef __attribute__((ext_vector_type(4))) float f32x4;

__device__ __forceinline__ float wave_sum(float x) {
#pragma unroll
    for (int off = 32; off > 0; off >>= 1) x += __shfl_xor(x, off);
    return x;
}
__device__ __forceinline__ float siluf(float x) {
    return x / (1.f + __expf(-x));
}
__device__ __forceinline__ float softplusf(float x) {
    return (x > 20.f) ? x : __logf(1.f + __expf(x));
}
__device__ __forceinline__ short f2bf(float x) {   // RNE f32 -> bf16
    unsigned u = __builtin_bit_cast(unsigned, x);
    u = (u + 0x7FFFu + ((u >> 16) & 1u)) >> 16;
    return (short)u;
}
__device__ __forceinline__ bf16x4 pack4(const float* f) {
    bf16x4 r;
#pragma unroll
    for (int j = 0; j < 4; ++j) r[j] = f2bf(f[j]);
    return r;
}
__device__ __forceinline__ bf16x8 pack8(const float* f) {
    bf16x8 r;
#pragma unroll
    for (int j = 0; j < 8; ++j) r[j] = f2bf(f[j]);
    return r;
}
// HW packed f32->bf16 (RNE): 8 floats -> bf16x8 (validated R2/R5 pattern)
__device__ __forceinline__ bf16x8 cvt8v(float4 a, float4 b) {
    unsigned u0, u1, u2, u3;
    asm("v_cvt_pk_bf16_f32 %0, %1, %2" : "=v"(u0) : "v"(a.x), "v"(a.y));
    asm("v_cvt_pk_bf16_f32 %0, %1, %2" : "=v"(u1) : "v"(a.z), "v"(a.w));
    asm("v_cvt_pk_bf16_f32 %0, %1, %2" : "=v"(u2) : "v"(b.x), "v"(b.y));
    asm("v_cvt_pk_bf16_f32 %0, %1, %2" : "=v"(u3) : "v"(b.z), "v"(b.w));
    union { unsigned u[4]; bf16x8 v; } r;
    r.u[0] = u0; r.u[1] = u1; r.u[2] = u2; r.u[3] = u3;
    return r.v;
}

// ---------------------------------------------------------------------------
// Zero-fill (for the atomic rowscale accumulators).
// ---------------------------------------------------------------------------
__global__ __launch_bounds__(256)
void zero_kernel(float* __restrict__ p, int n)
{
    const int i = blockIdx.x * 256 + threadIdx.x;
    if (i < n) p[i] = 0.f;
}

// ---------------------------------------------------------------------------
// One-shot xp_w swizzle to MFMA B-fragment order, zero-padded 40->48 rows.
// Pool: [L][3 nt][8 kt][64 lane][8 e] bf16.  Lane l of frag (nt,kt) holds
// xw[nt*16 + (l&15)][kt*32 + (l>>4)*8 + e]  (rows >= 40 are zero).
// ---------------------------------------------------------------------------
__global__ __launch_bounds__(256)
void cvtxw_kernel(const float* __restrict__ xw, short* __restrict__ dst)
{
    const int tid = blockIdx.x * 256 + threadIdx.x;
    if (tid >= LL * 24 * 64) return;
    const int lane = tid & 63;
    const int f = (tid >> 6) % 24;        // nt*8 + kt
    const int l = tid / (24 * 64);
    const int nt = f >> 3, kt = f & 7;
    const int row = nt * 16 + (lane & 15);
    const int kc = kt * 32 + (lane >> 4) * 8;
    float4 v0 = {0.f, 0.f, 0.f, 0.f}, v1 = {0.f, 0.f, 0.f, 0.f};
    if (row < 40) {
        const float* s = xw + ((size_t)l * 40 + row) * II + kc;
        v0 = *(const float4*)s;
        v1 = *(const float4*)(s + 4);
    }
    *(bf16x8*)(dst + ((size_t)tid) * 8) = cvt8v(v0, v1);
}

// ---------------------------------------------------------------------------
// bf16-MFMA GEMM (R8-validated): round-0 inner loop, BN=64, BM=32, BK=32,
// LDT=40, 2 barriers/tile, reg-prefetch. rs[m] = row sumsq (rsqrt applied
// here); rso = atomicAdd sumsq accumulator (pre-zeroed). A-side fusions:
// rs*cs (rmsnorm), silu(em) (gate, leading dim lde). Output split at nsplit.
// ---------------------------------------------------------------------------
#define LDT 40
template<bool ACCUM>
__global__ __launch_bounds__(256)
void gemm_mfma(const float* __restrict__ A, const float* __restrict__ W, int K,
               const float* __restrict__ A2, const float* __restrict__ W2, int K2,
               const float* __restrict__ bias,
               const float* __restrict__ r1x, const float* __restrict__ r1w,
               const float* __restrict__ rs, const float* __restrict__ cs,
               const float* __restrict__ em, int lde,
               float* __restrict__ C, float* __restrict__ C2, int nsplit, int ldc,
               float* __restrict__ rso)
{
    __shared__ __align__(16) short Asl[32 * LDT];
    __shared__ __align__(16) short Bsl[64 * LDT];
    __shared__ float red[2][32];
    const int bm = blockIdx.x * 32;
    const int bn = blockIdx.y * 64;
    const int t  = threadIdx.x;
    const int lane = t & 63;
    const int wave = t >> 6;
    const int wr = wave >> 1, wc = wave & 1;
    const int lrow = lane & 15;
    const int lk   = (lane >> 4) * 8;

    f32x4 acc[2];
    acc[0] = (f32x4){0.f, 0.f, 0.f, 0.f};
    acc[1] = (f32x4){0.f, 0.f, 0.f, 0.f};

    const int arow = t >> 3, ak = (t & 7) * 4;    // A: 32 rows x 32 k (4 f/thr)
    const int brow = t >> 2, bk = (t & 3) * 8;    // B: 64 rows x 32 k (8 f/thr)
    const float rsv = rs ? rsqrtf(rs[bm + arow] * (1.f / DM) + 1e-5f) : 1.f;

    float av[4], bv[8], cv[4], ev[4];

#pragma unroll 1
    for (int pass = 0; pass < 2; ++pass) {
        const float* Ap = pass ? A2 : A;
        const float* Wp = pass ? W2 : W;
        const int    Kp = pass ? K2 : K;
        if (!Ap) continue;
        const float* aptr = Ap + (size_t)(bm + arow) * Kp + ak;
        const float* bptr = Wp + (size_t)(bn + brow) * Kp + bk;
        const float* eptr = em ? em + (size_t)(bm + arow) * lde + ak : nullptr;

        // prologue load (k0 = 0)
        *(float4*)&av[0] = *(const float4*)(aptr);
        if (cs) *(float4*)&cv[0] = *(const float4*)&cs[ak];
        if (em) *(float4*)&ev[0] = *(const float4*)(eptr);
        *(float4*)&bv[0] = *(const float4*)(bptr);
        *(float4*)&bv[4] = *(const float4*)(bptr + 4);

#pragma unroll 1
        for (int k0 = 0; k0 < Kp; k0 += 32) {
            __syncthreads();   // previous iteration's LDS reads done
            float as[4];
#pragma unroll
            for (int j = 0; j < 4; ++j) {
                float v = av[j];
                if (cs) v *= rsv * cv[j];
                if (em) v *= siluf(ev[j]);
                as[j] = v;
            }
            *(bf16x4*)&Asl[arow * LDT + ak] = pack4(as);
            *(bf16x8*)&Bsl[brow * LDT + bk] = pack8(bv);
            __syncthreads();
            const int kn = k0 + 32;
            if (kn < Kp) {   // prefetch next tile while MFMA runs
                *(float4*)&av[0] = *(const float4*)(aptr + kn);
                if (cs) *(float4*)&cv[0] = *(const float4*)&cs[kn + ak];
                if (em) *(float4*)&ev[0] = *(const float4*)(eptr + kn);
                *(float4*)&bv[0] = *(const float4*)(bptr + kn);
                *(float4*)&bv[4] = *(const float4*)(bptr + kn + 4);
            }
            const bf16x8 af = *(const bf16x8*)&Asl[(wr * 16 + lrow) * LDT + lk];
            bf16x8 bfr[2];
#pragma unroll
            for (int ni = 0; ni < 2; ++ni)
                bfr[ni] = *(const bf16x8*)&Bsl[(wc * 32 + ni * 16 + lrow) * LDT + lk];
#pragma unroll
            for (int ni = 0; ni < 2; ++ni)
                acc[ni] = __builtin_amdgcn_mfma_f32_16x16x32_bf16(af, bfr[ni], acc[ni], 0, 0, 0);
        }
    }

    // epilogue (split + optional atomic rowscale sumsq)
    const bool hi = (bn >= nsplit);
    float* __restrict__ Cp = hi ? C2 : C;
    const int cb = bn - (hi ? nsplit : 0);
    float p[4] = {0.f, 0.f, 0.f, 0.f};
#pragma unroll
    for (int r = 0; r < 4; ++r) {
        const int row = bm + wr * 16 + (lane >> 4) * 4 + r;
        const float xl = r1x ? r1x[row] : 0.f;
#pragma unroll
        for (int ni = 0; ni < 2; ++ni) {
            const int col = bn + wc * 32 + ni * 16 + lrow;   // logical col
            float v = acc[ni][r];
            if (bias) v += bias[col];
            if (r1x)  v += xl * r1w[col];
            float* cp = &Cp[(size_t)row * ldc + (cb + wc * 32 + ni * 16 + lrow)];
            if (ACCUM) v += *cp;
            *cp = v;
            p[r] += v * v;
        }
    }
    if (rso) {   // partial sumsq (32 cols of this block) -> atomicAdd
#pragma unroll
        for (int m = 1; m < 16; m <<= 1) {
#pragma unroll
            for (int r = 0; r < 4; ++r) p[r] += __shfl_xor(p[r], m);
        }
        if (lrow == 0) {
#pragma unroll
            for (int r = 0; r < 4; ++r)
                red[wc][wr * 16 + (lane >> 4) * 4 + r] = p[r];
        }
        __syncthreads();
        if (t < 32) atomicAdd(&rso[bm + t], red[0][t] + red[1][t]);
    }
}

// ---------------------------------------------------------------------------
// Fused conv + x_proj + scanA per (b, chunk):
//  - causal depthwise conv(K=4)+SiLU -> uts (LDS) + ut (global, for scanB)
//  - x_proj via MFMA (R10): waves 0..2 each compute one 16x16 D-tile over
//    8 K-steps; A = uts rows (cvt_pk to bf16), B = pre-swizzled xws frags.
//    D mapping = proven gemm layout: col = nt*16+(lane&15), row=(lane>>4)*4+r.
//    Replaces the scalar-dot xproj (~40% of this kernel's VALU — R9 showed
//    the kernel is issue-throughput-bound, so instr count is the lever).
//  - scanA: local scan from zero init -> q; dtsum[b][ch][i] replaces P.
// ---------------------------------------------------------------------------
__global__ __launch_bounds__(256)
void fusedA_kernel(const float* __restrict__ hs, const float* __restrict__ cw,
                   const float* __restrict__ cb, const short* __restrict__ xws,
                   const float* __restrict__ dtw, const float* __restrict__ dtb,
                   const float* __restrict__ A_log,
                   float* __restrict__ ut, float* __restrict__ sp,
                   float* __restrict__ dtsum_g, float* __restrict__ q)
{
    __shared__ float uts[TCH][II + 4];   // 14 x 260
    __shared__ float lsp[TCH * 40];
    const int b = blockIdx.x;
    const int ch = blockIdx.y;
    const int i = threadIdx.x;
    const int s0 = ch * TCH;

    // ---- conv ----
    {
        const float4 w = *(const float4*)&cw[i * 4];
        const float bi = cb[i];
        const float* hp = hs + (size_t)b * SS * II + i;
        float* up = ut + (size_t)b * SS * II + i;
        float wm3 = (s0 - 3 >= 0) ? hp[(s0 - 3) * II] : 0.f;
        float wm2 = (s0 - 2 >= 0) ? hp[(s0 - 2) * II] : 0.f;
        float wm1 = (s0 - 1 >= 0) ? hp[(s0 - 1) * II] : 0.f;
        for (int s = 0; s < TCH; ++s) {
            const float cur = hp[(s0 + s) * II];
            float a = fmaf(w.x, wm3, fmaf(w.y, wm2, fmaf(w.z, wm1, fmaf(w.w, cur, bi))));
            const float uv = siluf(a);
            up[(s0 + s) * II] = uv;
            uts[s][i] = uv;
            wm3 = wm2; wm2 = wm1; wm1 = cur;
        }
    }
    __syncthreads();

    // ---- x_proj via MFMA (waves 0..2; wave 3 idles to the barrier) ----
    {
        const int lane = i & 63;
        const int wv = i >> 6;
        if (wv < 3) {
            const int lk = (lane >> 4) * 8;
            const int srow = lane & 15;          // A row (s index; 14/15 unused)
            const short* wp = xws + ((size_t)(wv * 8) * 64 + lane) * 8;
            f32x4 acc = (f32x4){0.f, 0.f, 0.f, 0.f};
#pragma unroll
            for (int kt = 0; kt < 8; ++kt) {
                const float* up = &uts[0][0] + srow * (II + 4) + kt * 32 + lk;
                const float4 a0 = *(const float4*)(up);
                const float4 a1 = *(const float4*)(up + 4);
                const bf16x8 af = cvt8v(a0, a1);
                const bf16x8 bf = *(const bf16x8*)(wp + (size_t)kt * 512);
                acc = __builtin_amdgcn_mfma_f32_16x16x32_bf16(af, bf, acc, 0, 0, 0);
            }
            const int col = wv * 16 + (lane & 15);
            const int r0 = (lane >> 4) * 4;
            if (col < 40) {
#pragma unroll
                for (int r = 0; r < 4; ++r)
                    if (r0 + r < TCH) lsp[(r0 + r) * 40 + col] = acc[r];
            }
        }
    }
    __syncthreads();

    // sp -> global (scanB needs it)
    {
        float* spp = sp + ((size_t)b * SS + s0) * 40;
        for (int idx = i; idx < TCH * 40; idx += 256) spp[idx] = lsp[idx];
    }

    // ---- scanA ----
    float dw[8];
    {
        const float4 w0 = *(const float4*)&dtw[i * 8];
        const float4 w1 = *(const float4*)&dtw[i * 8 + 4];
        dw[0]=w0.x; dw[1]=w0.y; dw[2]=w0.z; dw[3]=w0.w;
        dw[4]=w1.x; dw[5]=w1.y; dw[6]=w1.z; dw[7]=w1.w;
    }
    const float bdt = dtb[i];
    float Ar[NN];
#pragma unroll
    for (int n = 0; n < NN; ++n) Ar[n] = -__expf(A_log[i * NN + n]);

    float st[NN];
#pragma unroll
    for (int n = 0; n < NN; ++n) st[n] = 0.f;
    float dtsum = 0.f;

    for (int s = 0; s < TCH; ++s) {
        const float uv = uts[s][i];
        const float* r = &lsp[s * 40];
        const float p0 = fmaf(r[1], dw[1], r[0] * dw[0]);
        const float p1 = fmaf(r[3], dw[3], r[2] * dw[2]);
        const float p2 = fmaf(r[5], dw[5], r[4] * dw[4]);
        const float p3 = fmaf(r[7], dw[7], r[6] * dw[6]);
        const float dtv = softplusf(bdt + (p0 + p1) + (p2 + p3));
        const float du = dtv * uv;
        dtsum += dtv;
#pragma unroll
        for (int n = 0; n < NN; ++n) {
            const float a = __expf(dtv * Ar[n]);
            st[n] = fmaf(a, st[n], du * r[8 + n]);
        }
    }
    dtsum_g[((size_t)b * NCH + ch) * II + i] = dtsum;
    float* qp = q + (((size_t)b * NCH + ch) * NN) * II + i;
#pragma unroll
    for (int n = 0; n < NN; ++n) qp[n * II] = st[n];
}

// ---------------------------------------------------------------------------
// Combine: q[ch] <- state BEFORE chunk ch. thread = (b, i).
// P recomputed as exp(Ar[n] * dtsum[ch]).
// ---------------------------------------------------------------------------
__global__ __launch_bounds__(256)
void combine_kernel(const float* __restrict__ dtsum_g,
                    const float* __restrict__ A_log, float* __restrict__ q)
{
    const int b = blockIdx.x;
    const int i = threadIdx.x;
    float Ar[NN];
#pragma unroll
    for (int n = 0; n < NN; ++n) Ar[n] = -__expf(A_log[i * NN + n]);
    float ds[NCH];
#pragma unroll
    for (int ch = 0; ch < NCH; ++ch)
        ds[ch] = dtsum_g[((size_t)b * NCH + ch) * II + i];
#pragma unroll
    for (int n = 0; n < NN; ++n) {
        float cur = 0.f;
#pragma unroll
        for (int ch = 0; ch < NCH; ++ch) {
            const size_t idx = (((size_t)b * NCH + ch) * NN + n) * II + i;
            const float Pv = __expf(Ar[n] * ds[ch]);
            const float qv = q[idx];
            q[idx] = cur;
            cur = fmaf(Pv, cur, qv);
        }
    }
}

// ---------------------------------------------------------------------------
// Scan pass B: full scan with proper init; y = st·C + ut*Dp  (gate applied
// later inside the out_proj GEMM staging).
// ---------------------------------------------------------------------------
__global__ __launch_bounds__(256)
void scanB_kernel(const float* __restrict__ ut, const float* __restrict__ sp,
                  const float* __restrict__ qinit,
                  const float* __restrict__ dtw, const float* __restrict__ dtb,
                  const float* __restrict__ A_log, const float* __restrict__ Dp,
                  float* __restrict__ y)
{
    __shared__ float lsp[TCH * 40];
    const int b = blockIdx.x;
    const int ch = blockIdx.y;
    const int i = threadIdx.x;
    const int s0 = ch * TCH;
    {
        const float* spp = sp + ((size_t)b * SS + s0) * 40;
        for (int idx = i; idx < TCH * 40; idx += 256) lsp[idx] = spp[idx];
    }
    float dw[8];
    {
        const float4 w0 = *(const float4*)&dtw[i * 8];
        const float4 w1 = *(const float4*)&dtw[i * 8 + 4];
        dw[0]=w0.x; dw[1]=w0.y; dw[2]=w0.z; dw[3]=w0.w;
        dw[4]=w1.x; dw[5]=w1.y; dw[6]=w1.z; dw[7]=w1.w;
    }
    const float bdt = dtb[i];
    const float Dv = Dp[i];
    float Ar[NN];
#pragma unroll
    for (int n = 0; n < NN; ++n) Ar[n] = -__expf(A_log[i * NN + n]);

    float st[NN];
    {
        const float* qp = qinit + (((size_t)b * NCH + ch) * NN) * II + i;
#pragma unroll
        for (int n = 0; n < NN; ++n) st[n] = qp[n * II];
    }

    const float* utp = ut + ((size_t)b * SS + s0) * II + i;
    float* yp = y + ((size_t)b * SS + s0) * II + i;
    __syncthreads();

    float uv = utp[0];
    for (int s = 0; s < TCH; ++s) {
        const int sn = (s + 1 < TCH) ? s + 1 : s;
        const float uv_n = utp[sn * II];
        const float* r = &lsp[s * 40];
        const float p0 = fmaf(r[1], dw[1], r[0] * dw[0]);
        const float p1 = fmaf(r[3], dw[3], r[2] * dw[2]);
        const float p2 = fmaf(r[5], dw[5], r[4] * dw[4]);
        const float p3 = fmaf(r[7], dw[7], r[6] * dw[6]);
        const float dtv = softplusf(bdt + (p0 + p1) + (p2 + p3));
        const float du = dtv * uv;
        float y0 = 0.f, y1 = 0.f, y2 = 0.f, y3 = 0.f;
#pragma unroll
        for (int n = 0; n < NN; n += 4) {
            const float a0 = __expf(dtv * Ar[n + 0]);
            const float a1 = __expf(dtv * Ar[n + 1]);
            const float a2 = __expf(dtv * Ar[n + 2]);
            const float a3 = __expf(dtv * Ar[n + 3]);
            st[n + 0] = fmaf(a0, st[n + 0], du * r[8 + n + 0]);
            st[n + 1] = fmaf(a1, st[n + 1], du * r[8 + n + 1]);
            st[n + 2] = fmaf(a2, st[n + 2], du * r[8 + n + 2]);
            st[n + 3] = fmaf(a3, st[n + 3], du * r[8 + n + 3]);
            y0 = fmaf(st[n + 0], r[24 + n + 0], y0);
            y1 = fmaf(st[n + 1], r[24 + n + 1], y1);
            y2 = fmaf(st[n + 2], r[24 + n + 2], y2);
            y3 = fmaf(st[n + 3], r[24 + n + 3], y3);
        }
        yp[s * II] = (y0 + y1) + (y2 + y3) + uv * Dv;
        uv = uv_n;
    }
}

// ---------------------------------------------------------------------------
// Final head: rmsnorm(h[b,S-1,:]) -> layernorm -> fc -> out[b,p]
// ---------------------------------------------------------------------------
__global__ __launch_bounds__(64)
void final_kernel(const float* __restrict__ h, const float* __restrict__ fnw,
                  const float* __restrict__ lnw, const float* __restrict__ lnb,
                  const float* __restrict__ fcw, const float* __restrict__ fcb,
                  float* __restrict__ out)
{
    __shared__ float last[DM];
    const int b = blockIdx.x;
    const int lane = threadIdx.x;
    const float* hp = &h[((size_t)b * SS + (SS - 1)) * DM];
    const float2 v = *(const float2*)&hp[lane * 2];
    const float ss = wave_sum(v.x * v.x + v.y * v.y);
    const float sc = rsqrtf(ss * (1.f / DM) + 1e-5f);
    const float2 fw = *(const float2*)&fnw[lane * 2];
    const float t0 = v.x * sc * fw.x, t1 = v.y * sc * fw.y;
    const float m = wave_sum(t0 + t1) * (1.f / DM);
    const float d0 = t0 - m, d1 = t1 - m;
    const float var = wave_sum(d0 * d0 + d1 * d1) * (1.f / DM);
    const float iv = rsqrtf(var + 1e-5f);
    const float2 lw = *(const float2*)&lnw[lane * 2];
    const float2 lb = *(const float2*)&lnb[lane * 2];
    last[lane * 2]     = d0 * iv * lw.x + lb.x;
    last[lane * 2 + 1] = d1 * iv * lw.y + lb.y;
    __syncthreads();
    if (lane < PP) {
        float a = fcb[lane];
#pragma unroll 8
        for (int d = 0; d < DM; ++d) a = fmaf(last[d], fcw[lane * DM + d], a);
        out[b * PP + lane] = a;
    }
}

// ---------------------------------------------------------------------------
extern "C" void kernel_launch(void* const* d_in, const int* in_sizes, int n_in,
                              void* d_out, int out_size, void* d_ws, size_t ws_size,
                              hipStream_t stream)
{
    (void)in_sizes; (void)n_in; (void)out_size; (void)ws_size;
    const float* x_load = (const float*)d_in[0];
    const float* x_img  = (const float*)d_in[1];
    const float* x_text = (const float*)d_in[2];
    const float* Wl     = (const float*)d_in[3];
    const float* Wi     = (const float*)d_in[4];
    const float* Wt     = (const float*)d_in[5];
    const float* b_fuse = (const float*)d_in[6];
    const float* mnorm_w= (const float*)d_in[7];
    const float* in_w   = (const float*)d_in[8];
    const float* in_b   = (const float*)d_in[9];
    const float* conv_w = (const float*)d_in[10];
    const float* conv_b = (const float*)d_in[11];
    const float* xp_w   = (const float*)d_in[12];
    const float* dt_w   = (const float*)d_in[13];
    const float* dt_b   = (const float*)d_in[14];
    const float* A_log  = (const float*)d_in[15];
    const float* Dp     = (const float*)d_in[16];
    const float* out_w  = (const float*)d_in[17];
    const float* out_b  = (const float*)d_in[18];
    const float* fnorm_w= (const float*)d_in[19];
    const float* ln_w   = (const float*)d_in[20];
    const float* ln_b   = (const float*)d_in[21];
    const float* fc_w   = (const float*)d_in[22];
    const float* fc_b   = (const float*)d_in[23];

    float* ws  = (float*)d_ws;
    float* h     = ws;                              // [21504][128]
    float* ybuf  = h     + (size_t)MROWS * DM;      // [21504][256] (y; dtsum alias)
    float* hs    = ybuf  + (size_t)MROWS * II;      // [21504][256]
    float* gate  = hs    + (size_t)MROWS * II;      // [21504][256]
    float* ut    = gate  + (size_t)MROWS * II;      // [21504][256]
    float* sp    = ut    + (size_t)MROWS * II;      // [21504][40]
    float* scale0= sp    + (size_t)MROWS * 40;      // [21504] sumsq (fusion)
    float* scale1= scale0 + MROWS;                  // [21504] sumsq (out_proj l0)
    float* q     = scale1 + MROWS;                  // [B][NCH][NN][II] dedicated
    short* xwpool= (short*)(q + (size_t)BB * NCH * NN * II);  // [L][24][64][8] bf16
    float* dtsum = ybuf;                            // [B][NCH][II] (dead before y)

    const int NSP_NONE = 1 << 30;

    // zero the atomic sumsq accumulators + swizzle xp_w (one-shot)
    zero_kernel<<<(2 * MROWS + 255) / 256, 256, 0, stream>>>(scale0, 2 * MROWS);
    cvtxw_kernel<<<(LL * 24 * 64 + 255) / 256, 256, 0, stream>>>(xp_w, xwpool);

    // --- feature fusion (text + img + rank-1 load + bias), sumsq fused ---
    gemm_mfma<false><<<dim3(MROWS / 32, 2), 256, 0, stream>>>(
        x_text, Wt, 768, x_img, Wi, 64, b_fuse, x_load, Wl,
        nullptr, nullptr, nullptr, 0,
        h, nullptr, NSP_NONE, DM, scale0);

    for (int l = 0; l < LL; ++l) {
        const float* sc_in = (l == 0) ? scale0 : scale1;
        // in_proj (rmsnorm fused via rs(sumsq)/cs), hs+gate in ONE dispatch:
        // blocks with logical col < 256 -> hs, >= 256 -> gate.
        gemm_mfma<false><<<dim3(MROWS / 32, 8), 256, 0, stream>>>(
            h, in_w + (size_t)l * 2 * II * DM, DM, nullptr, nullptr, 0,
            in_b + (size_t)l * 2 * II, nullptr, nullptr,
            sc_in, mnorm_w + l * DM, nullptr, 0,
            hs, gate, II, II, nullptr);
        // conv + x_proj(MFMA) + scanA fused
        fusedA_kernel<<<dim3(BB, NCH), 256, 0, stream>>>(
            hs, conv_w + l * II * KK, conv_b + l * II, xwpool + (size_t)l * 24 * 512,
            dt_w + l * II * RR, dt_b + l * II, A_log + l * II * NN,
            ut, sp, dtsum, q);
        combine_kernel<<<BB, 256, 0, stream>>>(dtsum, A_log + l * II * NN, q);
        scanB_kernel<<<dim3(BB, NCH), 256, 0, stream>>>(
            ut, sp, q, dt_w + l * II * RR, dt_b + l * II,
            A_log + l * II * NN, Dp + l * II, ybuf);
        // out_proj with y*silu(gate) fused into A staging; next layer's
        // rmsnorm sumsq accumulated atomically (only needed after l=0).
        gemm_mfma<true><<<dim3(MROWS / 32, 2), 256, 0, stream>>>(
            ybuf, out_w + (size_t)l * DM * II, II, nullptr, nullptr, 0,
            out_b + l * DM, nullptr, nullptr,
            nullptr, nullptr, gate, II,
            h, nullptr, NSP_NONE, DM, (l == 0) ? scale1 : nullptr);
    }

    final_kernel<<<BB, 64, 0, stream>>>(h, fnorm_w, ln_w, ln_b, fc_w, fc_b,
                                        (float*)d_out);
}